// Round 3
// baseline (215.980 us; speedup 1.0000x reference)
//
#include <hip/hip_runtime.h>
#include <cstdint>
#include <cstddef>

typedef __attribute__((ext_vector_type(8))) short short8;
typedef __attribute__((ext_vector_type(4))) float floatx4;

typedef __attribute__((address_space(1))) const void gvoid_t;
typedef __attribute__((address_space(3))) void lvoid_t;

// fp32 -> bf16 with round-to-nearest-even (bit pattern as short)
__device__ inline short f2bf(float f) {
    unsigned u = __float_as_uint(f);
    u = (u + 0x7FFFu + ((u >> 16) & 1u)) >> 16;
    return (short)u;
}

// ---------------------------------------------------------------------------
// Merged prologue: blocks [0,ncvt) convert x fp32->bf16; [ncvt,ncvt+ndq)
// dequantize qweight into transposed bf16 deqT [N][K]; remaining blocks
// initialize C[m][n] = bias[n] (split-K GEMM accumulates into C atomically).
// All memory-bound; ~120MB total ~= 19us at 6.3 TB/s.
// ---------------------------------------------------------------------------
__global__ __launch_bounds__(256) void prologue_kernel(
    const float* __restrict__ x, short* __restrict__ xb, long long nx, int ncvt,
    const int* __restrict__ qw, const float* __restrict__ scales,
    const float* __restrict__ zps, short* __restrict__ deqT,
    int N, int K, int nbx, int ndq,
    const float* __restrict__ bias, float* __restrict__ C, long long mn)
{
    __shared__ int lds_q[32 * 65];
    const int t = threadIdx.x;
    const int bid = (int)blockIdx.x;

    if (bid < ncvt) {
        // ---- convert x ----
        long long i = ((long long)bid * 256 + t) * 8;
        if (i + 8 > nx) return;
        const float4* p = (const float4*)(x + i);
        float4 v0 = p[0];
        float4 v1 = p[1];
        short8 h;
        h[0] = f2bf(v0.x); h[1] = f2bf(v0.y); h[2] = f2bf(v0.z); h[3] = f2bf(v0.w);
        h[4] = f2bf(v1.x); h[5] = f2bf(v1.y); h[6] = f2bf(v1.z); h[7] = f2bf(v1.w);
        *(short8*)(xb + i) = h;
        return;
    }

    if (bid < ncvt + ndq) {
        // ---- dequant ----
        const int b2 = bid - ncvt;
        const int n0 = (b2 % nbx) * 64;
        const int r0 = (b2 / nbx) * 32;   // qweight row tile (32 rows = 256 k)

        #pragma unroll
        for (int v = 0; v < 2; ++v) {
            int idx = t + v * 256;            // 0..511 int4-chunks
            int row = idx >> 4;               // 16 int4 per 64-col row
            int c4  = (idx & 15) * 4;
            const int4 q4 = *(const int4*)(qw + (size_t)(r0 + row) * N + n0 + c4);
            int base = row * 65 + c4;
            lds_q[base + 0] = q4.x;
            lds_q[base + 1] = q4.y;
            lds_q[base + 2] = q4.z;
            lds_q[base + 3] = q4.w;
        }
        __syncthreads();

        const int L  = t & 63;
        const int w  = t >> 6;
        const int rq = L & 31;
        const int hi = L >> 5;
        const int g  = (r0 + rq) >> 4;

        #pragma unroll
        for (int it = 0; it < 8; ++it) {
            const int p  = w * 8 + it;
            const int nl = 2 * p + hi;

            float s = scales[(size_t)g * N + n0 + nl];
            s = fminf(fmaxf(s, 1e-5f), 1e4f);
            float z = rintf(zps[(size_t)g * N + n0 + nl]);
            z = fminf(fmaxf(z, 0.0f), 15.0f);

            const int q = lds_q[rq * 65 + nl];
            short8 h;
            #pragma unroll
            for (int j = 0; j < 8; ++j) {
                float f = (float)((q >> (4 * j)) & 15);
                h[j] = f2bf((f - z) * s);
            }
            *(short8*)(deqT + (size_t)(n0 + nl) * K + (size_t)(r0 + rq) * 8) = h;
        }
        return;
    }

    // ---- C := bias (row-broadcast), 8 floats/thread ----
    long long i = ((long long)(bid - ncvt - ndq) * 256 + t) * 8;
    if (i + 8 > mn) return;
    const int col = (int)(i % (long long)N);   // N % 8 == 0 -> same row segment
    const float4 b0 = *(const float4*)(bias + col);
    const float4 b1 = *(const float4*)(bias + col + 4);
    float4* o = (float4*)(C + i);
    o[0] = b0; o[1] = b1;
}

// ---------------------------------------------------------------------------
// Kernel 2: bf16 GEMM, C += A[M][K] * Bt[N][K]^T (C pre-init = bias), fp32.
//
// R11: faithful port of the proven 256^2 8-phase structure (learn_hip
// m198/m201: the ONLY plain-HIP config measured >900 TF; R2's 2-phase
// landed at 761 TF = the documented "2-phase band"). M=2048 gives only
// 8x16 = 128 tile-blocks at 256^2, so SPLIT-K=2: grid = 256 blocks = 1/CU,
// each block covers K-half kb..kb+K/2, accumulating into C via fp32
// atomicAdd (C pre-initialized to bias by the prologue; same stream).
//
// Geometry: 512 thr = 8 waves (2m x 4n), per-wave 128x64 output ->
// acc[8][4] (128 AGPR), A register-held (16 ds_read_b128/tile), B streamed
// (1 n-frag x 2 ksteps per phase). 4 phases per K-tile, 16 MFMA each.
//
// LDS: per operand a 4-slot HALF-TILE ring (4 x 128rows x 64 x 2B = 64KB;
// 128KB total). Half h of K-tile ti lives in slot (2ti+h)&3. Staging: one
// half-tile (2 global_load_lds) per phase: P1->Ah0(ti+1), P2->Ah1(ti+1),
// P3->Bh0(ti+1), P4->Bh1(ti+1). Slot WAR: the target slot was last READ
// >=1 full tile earlier (A slots free after P1(ti)'s lgkm+barrier; B after
// P4(ti)); all staging lands >=4 phases after that barrier.
//
// Counted waits (never 0 in steady state), per-wave in-flight ledger:
//   entering P1(ti): {Bh0,Bh1}(ti) = 4 loads  (A(ti) retired at boundary)
//   P1: +Ah0(ti+1) -> 6; vmcnt(2) retires B(ti) [needed by P1/P2/P3 reads],
//       keeps Ah0(ti+1); then barrier publishes B(ti) to all waves.
//   P4: in-flight = A(ti+1) 4 + B(ti+1) 4; vmcnt(4) retires A(ti+1)
//       [needed by P1(ti+1)'s 16 A-reads], keeps B(ti+1); barrier publishes.
// lgkm counts: P1 issues [16 A + 2 B-f0] | sched_barrier | [2 B-f1];
// lgkmcnt(2) -> A+f0 done, f1 pends into P2. P2/P3 issue next frag pre-
// barrier (reads tile-ti slots, resident since P1's barrier): lgkmcnt(2).
// P4: lgkmcnt(0). setprio(1) around each 16-MFMA cluster (T5).
// ---------------------------------------------------------------------------
__global__ __launch_bounds__(512, 2) void gemm_bf16_sk(
    const short* __restrict__ A, const short* __restrict__ Bt,
    float* __restrict__ C, int M, int N, int K)
{
    __shared__ __align__(16) short a_lds[4][128 * 64];   // 64 KB ring
    __shared__ __align__(16) short b_lds[4][128 * 64];   // 64 KB ring

    const int t = threadIdx.x;
    const int L = t & 63;
    const int w = t >> 6;            // 0..7

    // Block mapping: XCD k owns n-tiles {2k,2k+1} x all m x both splits
    // (32 blocks/XCD); the two split-halves of a tile share an XCD L2 ->
    // cheap atomic combining + B-panel (4MB) resident. G16-safe.
    const int mtiles = M >> 8, ntiles = N >> 8;
    int mt, nt, sk;
    if (mtiles == 8 && ntiles == 16) {
        const int id = blockIdx.x;
        const int loc = id >> 3;
        mt = loc & 7;
        nt = (id & 7) * 2 + ((loc >> 3) & 1);
        sk = (loc >> 4) & 1;
    } else {
        const int tpg = mtiles * ntiles;
        sk = blockIdx.x / tpg;
        const int r = blockIdx.x % tpg;
        nt = r % ntiles; mt = r / ntiles;
    }
    const int KH = K >> 1;
    const int m0 = mt << 8, n0 = nt << 8, kb = sk * KH;
    const int NT = KH / 64;

    const int hA  = w & 1;            // wave's A half (rows hA*128..+127)
    const int wn  = (w >> 1) * 64;    // wave's B quarter
    const int rBb = wn & 127;         // row base within B half-slot
    const int hB  = w >> 2;           // wave's B half
    const int l15 = L & 15, l4 = L >> 4, l7 = L & 7;
    const int p0 = l4 ^ l7, p1 = (4 + l4) ^ l7;   // swizzled chunk positions
    const int sr = L >> 3, sc = L & 7, gc = sc ^ sr;

    const short* agp = A  + (size_t)(m0 + w * 8 + sr) * K + kb + gc * 8;
    const short* bgp = Bt + (size_t)(n0 + w * 8 + sr) * K + kb + gc * 8;
    const int dstw = (w * 8) * 64;    // wave-uniform LDS offset (shorts)

    floatx4 acc[8][4] = {};

#define STG_A(tn_, h_) do { \
    const int st_ = (2 * (tn_) + (h_)) & 3; \
    const size_t ko_ = (size_t)(tn_) * 64; \
    __builtin_amdgcn_global_load_lds((gvoid_t*)(agp + (size_t)((h_) * 128) * K + ko_), \
        (lvoid_t*)(&a_lds[st_][dstw]), 16, 0, 0); \
    __builtin_amdgcn_global_load_lds((gvoid_t*)(agp + (size_t)((h_) * 128 + 64) * K + ko_), \
        (lvoid_t*)(&a_lds[st_][dstw + 64 * 64]), 16, 0, 0); \
} while (0)

#define STG_B(tn_, h_) do { \
    const int st_ = (2 * (tn_) + (h_)) & 3; \
    const size_t ko_ = (size_t)(tn_) * 64; \
    __builtin_amdgcn_global_load_lds((gvoid_t*)(bgp + (size_t)((h_) * 128) * K + ko_), \
        (lvoid_t*)(&b_lds[st_][dstw]), 16, 0, 0); \
    __builtin_amdgcn_global_load_lds((gvoid_t*)(bgp + (size_t)((h_) * 128 + 64) * K + ko_), \
        (lvoid_t*)(&b_lds[st_][dstw + 64 * 64]), 16, 0, 0); \
} while (0)

#define MFMA16(j_, bx0_, bx1_) do { \
    __builtin_amdgcn_s_setprio(1); \
    _Pragma("unroll") \
    for (int i_ = 0; i_ < 8; ++i_) { \
        acc[i_][j_] = __builtin_amdgcn_mfma_f32_16x16x32_bf16(ah0[i_], bx0_, acc[i_][j_], 0, 0, 0); \
        acc[i_][j_] = __builtin_amdgcn_mfma_f32_16x16x32_bf16(ah1[i_], bx1_, acc[i_][j_], 0, 0, 0); \
    } \
    __builtin_amdgcn_s_setprio(0); \
} while (0)

    // pipeline fill: tile 0 fully staged (8 loads in flight)
    STG_A(0, 0); STG_A(0, 1); STG_B(0, 0); STG_B(0, 1);

    for (int ti = 0; ti < NT; ++ti) {
        const bool g = (ti + 1 < NT);
        const short* Ab = &a_lds[(2 * ti + hA) & 3][0];
        const short* Bb = &b_lds[(2 * ti + hB) & 3][0];
        short8 ah0[8], ah1[8];
        short8 b00, b01, b10, b11, b20, b21, b30, b31;

        // ---- P1: stage Ah0(ti+1); vmcnt(2) [B(ti) ready]; barrier;
        //          read A-hold(16) + B f0,f1; lgkmcnt(2); MFMA j=0.
        if (g) {
            STG_A(ti + 1, 0);
            asm volatile("s_waitcnt vmcnt(2)" ::: "memory");
        } else {
            asm volatile("s_waitcnt vmcnt(0)" ::: "memory");
        }
        __builtin_amdgcn_s_barrier();
        #pragma unroll
        for (int i = 0; i < 8; ++i) {
            ah0[i] = *(const short8*)(Ab + (16 * i + l15) * 64 + p0 * 8);
            ah1[i] = *(const short8*)(Ab + (16 * i + l15) * 64 + p1 * 8);
        }
        b00 = *(const short8*)(Bb + (rBb + l15) * 64 + p0 * 8);
        b01 = *(const short8*)(Bb + (rBb + l15) * 64 + p1 * 8);
        __builtin_amdgcn_sched_barrier(0);    // pin issue order: [A,f0] then [f1]
        b10 = *(const short8*)(Bb + (rBb + 16 + l15) * 64 + p0 * 8);
        b11 = *(const short8*)(Bb + (rBb + 16 + l15) * 64 + p1 * 8);
        asm volatile("s_waitcnt lgkmcnt(2)" ::: "memory");
        __builtin_amdgcn_sched_barrier(0);
        MFMA16(0, b00, b01);
        __builtin_amdgcn_s_barrier();

        // ---- P2: prefetch B f2 (tile-ti slot, resident); stage Ah1(ti+1);
        //          barrier; lgkmcnt(2) [f1 ready]; MFMA j=1.
        b20 = *(const short8*)(Bb + (rBb + 32 + l15) * 64 + p0 * 8);
        b21 = *(const short8*)(Bb + (rBb + 32 + l15) * 64 + p1 * 8);
        if (g) STG_A(ti + 1, 1);
        __builtin_amdgcn_s_barrier();
        asm volatile("s_waitcnt lgkmcnt(2)" ::: "memory");
        __builtin_amdgcn_sched_barrier(0);
        MFMA16(1, b10, b11);
        __builtin_amdgcn_s_barrier();

        // ---- P3: prefetch B f3; stage Bh0(ti+1); barrier; lgkmcnt(2); j=2.
        b30 = *(const short8*)(Bb + (rBb + 48 + l15) * 64 + p0 * 8);
        b31 = *(const short8*)(Bb + (rBb + 48 + l15) * 64 + p1 * 8);
        if (g) STG_B(ti + 1, 0);
        __builtin_amdgcn_s_barrier();
        asm volatile("s_waitcnt lgkmcnt(2)" ::: "memory");
        __builtin_amdgcn_sched_barrier(0);
        MFMA16(2, b20, b21);
        __builtin_amdgcn_s_barrier();

        // ---- P4: stage Bh1(ti+1); barrier; lgkmcnt(0); MFMA j=3;
        //          boundary vmcnt(4) [A(ti+1) ready, B(ti+1) in flight].
        if (g) STG_B(ti + 1, 1);
        __builtin_amdgcn_s_barrier();
        asm volatile("s_waitcnt lgkmcnt(0)" ::: "memory");
        __builtin_amdgcn_sched_barrier(0);
        MFMA16(3, b30, b31);
        if (g) asm volatile("s_waitcnt vmcnt(4)" ::: "memory");
        __builtin_amdgcn_s_barrier();
    }

    // Epilogue: C/D layout col = lane&15, row = (lane>>4)*4 + reg (m89/m91).
    // Split-K partial -> fp32 atomicAdd into C (pre-initialized to bias).
    const int col0 = n0 + wn + l15;
    #pragma unroll
    for (int i = 0; i < 8; ++i) {
        const int row0 = m0 + hA * 128 + 16 * i + l4 * 4;
        #pragma unroll
        for (int r = 0; r < 4; ++r) {
            float* cr = C + (size_t)(row0 + r) * N + col0;
            #pragma unroll
            for (int j = 0; j < 4; ++j)
                atomicAdd(cr + 16 * j, acc[i][j][r]);
        }
    }
#undef STG_A
#undef STG_B
#undef MFMA16
}

// ---------------------------------------------------------------------------
extern "C" void kernel_launch(void* const* d_in, const int* in_sizes, int n_in,
                              void* d_out, int out_size, void* d_ws, size_t ws_size,
                              hipStream_t stream)
{
    const float* x      = (const float*)d_in[0];
    const float* scales = (const float*)d_in[1];
    const float* zps    = (const float*)d_in[2];
    const float* bias   = (const float*)d_in[3];
    const int*   qw     = (const int*)d_in[4];

    const int N = in_sizes[3];          // outfeatures (bias length)
    const int G = in_sizes[1] / N;      // num groups
    const int K = G * 128;              // infeatures
    const int M = in_sizes[0] / K;      // tokens

    short* xb   = (short*)d_ws;                       // M*K bf16
    short* deqT = xb + (size_t)M * K;                 // N*K bf16
    float* out  = (float*)d_out;

    const long long nx = (long long)M * K;
    const long long mn = (long long)M * N;
    const int ncvt  = (int)(nx / 2048);
    const int nbx   = N / 64;
    const int ndq   = nbx * (K / 256);
    const int nbias = (int)(mn / 2048);

    prologue_kernel<<<ncvt + ndq + nbias, 256, 0, stream>>>(
        x, xb, nx, ncvt, qw, scales, zps, deqT, N, K, nbx, ndq, bias, out, mn);
    gemm_bf16_sk<<<2 * (M / 256) * (N / 256), 512, 0, stream>>>(
        xb, deqT, out, M, N, K);
}

// Round 4
// 173.776 us; speedup vs baseline: 1.2429x; 1.2429x over previous
//
#include <hip/hip_runtime.h>
#include <cstdint>
#include <cstddef>

typedef __attribute__((ext_vector_type(8))) short short8;
typedef __attribute__((ext_vector_type(16))) float floatx16;

typedef __attribute__((address_space(1))) const void gvoid_t;
typedef __attribute__((address_space(3))) void lvoid_t;

// fp32 -> bf16 with round-to-nearest-even (bit pattern as short)
__device__ inline short f2bf(float f) {
    unsigned u = __float_as_uint(f);
    u = (u + 0x7FFFu + ((u >> 16) & 1u)) >> 16;
    return (short)u;
}

// ---------------------------------------------------------------------------
// Merged prologue: blocks [0,ncvt) convert x fp32->bf16; blocks [ncvt,..)
// dequantize qweight into transposed bf16 deqT [N][K]. Both memory-bound,
// measured jointly ~15us ~= 88MB/6.3TBps roofline. (Identical to R0.)
// ---------------------------------------------------------------------------
__global__ __launch_bounds__(256) void prologue_kernel(
    const float* __restrict__ x, short* __restrict__ xb, long long nx, int ncvt,
    const int* __restrict__ qw, const float* __restrict__ scales,
    const float* __restrict__ zps, short* __restrict__ deqT,
    int N, int K, int nbx)
{
    __shared__ int lds_q[32 * 65];
    const int t = threadIdx.x;

    if ((int)blockIdx.x < ncvt) {
        // ---- convert x ----
        long long i = ((long long)blockIdx.x * 256 + t) * 8;
        if (i + 8 > nx) return;
        const float4* p = (const float4*)(x + i);
        float4 v0 = p[0];
        float4 v1 = p[1];
        short8 h;
        h[0] = f2bf(v0.x); h[1] = f2bf(v0.y); h[2] = f2bf(v0.z); h[3] = f2bf(v0.w);
        h[4] = f2bf(v1.x); h[5] = f2bf(v1.y); h[6] = f2bf(v1.z); h[7] = f2bf(v1.w);
        *(short8*)(xb + i) = h;
        return;
    }

    // ---- dequant ----
    const int b2 = (int)blockIdx.x - ncvt;
    const int n0 = (b2 % nbx) * 64;
    const int r0 = (b2 / nbx) * 32;   // qweight row tile (32 rows = 256 k)

    #pragma unroll
    for (int v = 0; v < 2; ++v) {
        int idx = t + v * 256;            // 0..511 int4-chunks
        int row = idx >> 4;               // 16 int4 per 64-col row
        int c4  = (idx & 15) * 4;
        const int4 q4 = *(const int4*)(qw + (size_t)(r0 + row) * N + n0 + c4);
        int base = row * 65 + c4;
        lds_q[base + 0] = q4.x;
        lds_q[base + 1] = q4.y;
        lds_q[base + 2] = q4.z;
        lds_q[base + 3] = q4.w;
    }
    __syncthreads();

    const int L  = t & 63;
    const int w  = t >> 6;
    const int rq = L & 31;            // qw row this lane unpacks
    const int hi = L >> 5;            // 0: row 2p, 1: row 2p+1
    const int g  = (r0 + rq) >> 4;    // quant group of this lane's 8 k-values

    #pragma unroll
    for (int it = 0; it < 8; ++it) {
        const int p  = w * 8 + it;    // row-pair index 0..31
        const int nl = 2 * p + hi;    // local n row 0..63

        float s = scales[(size_t)g * N + n0 + nl];
        s = fminf(fmaxf(s, 1e-5f), 1e4f);
        float z = rintf(zps[(size_t)g * N + n0 + nl]);
        z = fminf(fmaxf(z, 0.0f), 15.0f);

        const int q = lds_q[rq * 65 + nl];
        short8 h;
        #pragma unroll
        for (int j = 0; j < 8; ++j) {
            float f = (float)((q >> (4 * j)) & 15);
            h[j] = f2bf((f - z) * s);
        }
        // lanes 0-31: 512B contiguous (row 2p), lanes 32-63: row 2p+1
        *(short8*)(deqT + (size_t)(n0 + nl) * K + (size_t)(r0 + rq) * 8) = h;
    }
}

// ---------------------------------------------------------------------------
// Kernel 2: bf16 GEMM, C = A[M][K] * Bt[N][K]^T + bias, fp32 out.
//
// R12 = R0 (best measured: 78us GEMM, 888 TF, 0 bank conflicts, 2 blocks/CU)
// with ONE change: 16x16x32 MFMA -> 32x32x16 MFMA. Evidence:
//  (1) R0's FETCH 82MB = xb 16.8 + deqT 33.6 + ~33.5MB of C RFO fills: the
//      16x16 epilogue stores 64B row-segments (partial cache lines). The
//      32x32 C/D layout (col=lane&31, verified m74/m101) makes every store
//      instruction cover 32 contiguous fp32 = 128B full lines -> no RFO.
//  (2) 32x32 matrix pipe: 8.07 cyc / 32k FLOP vs 16x16's 4.85 / 16k
//      (m119/m06) -> ~13-17% fewer matrix-pipe cycles; half the MFMA insts.
// Everything else byte-identical to R0: single-barrier double-buffered BK=64
// loop, 2x(16+16)KB LDS, XCD-aware swizzle, same XOR chunk swizzle (rows
// congruent mod 8 -> identical conflict-free bank pattern).
//
// 32x32x16 operand layout (canonical gfx9 family, same pattern the working
// 16x16x32 code uses): A/Bt fragment = row (lane&31), k = 8*(lane>>5)..+7
// within the 16-wide kstep -> global k-chunk c = 2*ks + (lane>>5), read at
// swizzled pos p = c ^ (row&7). C/D: col = lane&31,
// row = (reg&3) + 8*(reg>>2) + 4*(lane>>5)  [m74/m101].
// ---------------------------------------------------------------------------
#define BM 128
#define BN 128
#define BK 64

__global__ __launch_bounds__(256) void gemm_bf16_bt(
    const short* __restrict__ A, const short* __restrict__ Bt,
    const float* __restrict__ bias, float* __restrict__ C,
    int M, int N, int K)
{
    __shared__ __align__(16) short a_lds[2][BM * BK];   // 2 x 16 KB
    __shared__ __align__(16) short b_lds[2][BN * BK];   // 2 x 16 KB

    const int t  = threadIdx.x;
    const int L  = t & 63;
    const int w  = t >> 6;

    // XCD swizzle: id%8 = XCD (dispatch round-robins consecutive ids across
    // XCDs). XCD k gets n-tiles 4k..4k+3 for every m-tile. (As R0.)
    const int nbn = N / BN;                    // n-tiles (32)
    const int id  = blockIdx.y * gridDim.x + blockIdx.x;
    const int xcd = id & 7;
    const int loc = id >> 3;                   // 0..63 per XCD
    const int gsz = nbn / 8;                   // n-tiles per XCD group (4)
    const int nt  = xcd * gsz + (loc % gsz);
    const int mt  = loc / gsz;
    const int m0  = mt * BM;
    const int n0  = nt * BN;

    const int wm = (w & 1) * 64;
    const int wn = (w >> 1) * 64;

    floatx16 acc[2][2] = {};

    // staging: per inst i, wave w covers rows w*8 + 32*i + (L>>3);
    // LDS slot = uniform base + lane*16B (hardware-enforced order).
    const int sr = L >> 3;            // row within the wave's 8-row window
    const int sc = L & 7;             // 16B-chunk position within row (0..7)
    const int gc = sc ^ sr;           // global chunk staged at LDS pos sc
    const short* ag = A  + (size_t)(m0 + w * 8 + sr) * K + gc * 8;
    const short* bg = Bt + (size_t)(n0 + w * 8 + sr) * K + gc * 8;
    const int dst = (w * 8) * BK;     // wave-uniform offset within buffer

    const int NK = K / BK;

    // prologue: stage tile 0 into buffer 0
    #pragma unroll
    for (int i = 0; i < 4; ++i) {
        __builtin_amdgcn_global_load_lds(
            (gvoid_t*)(ag + (size_t)i * 32 * K),
            (lvoid_t*)(&a_lds[0][dst + i * 32 * BK]), 16, 0, 0);
        __builtin_amdgcn_global_load_lds(
            (gvoid_t*)(bg + (size_t)i * 32 * K),
            (lvoid_t*)(&b_lds[0][dst + i * 32 * BK]), 16, 0, 0);
    }

    const int l31 = L & 31, l5 = L >> 5, l7 = L & 7;

    for (int ti = 0; ti < NK; ++ti) {
        const int cur = ti & 1;
        // drains cur's loads (in flight for a full compute phase, except ti=0)
        // + guarantees all waves finished reading buf cur^1
        __syncthreads();

        if (ti + 1 < NK) {
            const int kn = (ti + 1) * BK;
            #pragma unroll
            for (int i = 0; i < 4; ++i) {
                __builtin_amdgcn_global_load_lds(
                    (gvoid_t*)(ag + (size_t)i * 32 * K + kn),
                    (lvoid_t*)(&a_lds[cur ^ 1][dst + i * 32 * BK]), 16, 0, 0);
                __builtin_amdgcn_global_load_lds(
                    (gvoid_t*)(bg + (size_t)i * 32 * K + kn),
                    (lvoid_t*)(&b_lds[cur ^ 1][dst + i * 32 * BK]), 16, 0, 0);
            }
        }

        #pragma unroll
        for (int h = 0; h < 2; ++h) {
            // phase h covers ksteps 2h, 2h+1 (16 k each):
            // lane's global k-chunk c = 2*ks + l5, swizzled pos p = c ^ l7.
            short8 af[2][2], bfr[2][2];
            #pragma unroll
            for (int q = 0; q < 2; ++q) {
                const int p = (4 * h + 2 * q + l5) ^ l7;
                #pragma unroll
                for (int i = 0; i < 2; ++i)
                    af[i][q] = *(const short8*)(&a_lds[cur][(wm + 32 * i + l31) * BK + p * 8]);
                #pragma unroll
                for (int j = 0; j < 2; ++j)
                    bfr[j][q] = *(const short8*)(&b_lds[cur][(wn + 32 * j + l31) * BK + p * 8]);
            }
            #pragma unroll
            for (int q = 0; q < 2; ++q) {
                #pragma unroll
                for (int i = 0; i < 2; ++i) {
                    #pragma unroll
                    for (int j = 0; j < 2; ++j)
                        acc[i][j] = __builtin_amdgcn_mfma_f32_32x32x16_bf16(
                            af[i][q], bfr[j][q], acc[i][j], 0, 0, 0);
                }
            }
        }
    }

    // Epilogue: 32x32 C/D layout: col = lane&31,
    // row = (reg&3) + 8*(reg>>2) + 4*(lane>>5)   (m74/m101).
    // Each store: 32 lanes cover 32 contiguous fp32 = 128B full cache line.
    float bv[2];
    #pragma unroll
    for (int j = 0; j < 2; ++j)
        bv[j] = bias[n0 + wn + 32 * j + l31];
    const int col0 = n0 + wn + l31;
    #pragma unroll
    for (int i = 0; i < 2; ++i) {
        #pragma unroll
        for (int rg = 0; rg < 4; ++rg) {
            #pragma unroll
            for (int q = 0; q < 4; ++q) {
                const int row = m0 + wm + 32 * i + rg * 8 + q + 4 * l5;
                const int r   = rg * 4 + q;
                float* outr = C + (size_t)row * N + col0;
                outr[0]  = acc[i][0][r] + bv[0];
                outr[32] = acc[i][1][r] + bv[1];
            }
        }
    }
}

// ---------------------------------------------------------------------------
extern "C" void kernel_launch(void* const* d_in, const int* in_sizes, int n_in,
                              void* d_out, int out_size, void* d_ws, size_t ws_size,
                              hipStream_t stream)
{
    const float* x      = (const float*)d_in[0];
    const float* scales = (const float*)d_in[1];
    const float* zps    = (const float*)d_in[2];
    const float* bias   = (const float*)d_in[3];
    const int*   qw     = (const int*)d_in[4];

    const int N = in_sizes[3];          // outfeatures (bias length)
    const int G = in_sizes[1] / N;      // num groups
    const int K = G * 128;              // infeatures
    const int M = in_sizes[0] / K;      // tokens

    short* xb   = (short*)d_ws;                       // M*K bf16
    short* deqT = xb + (size_t)M * K;                 // N*K bf16
    float* out  = (float*)d_out;

    const long long nx = (long long)M * K;
    const int ncvt = (int)(nx / 2048);
    const int nbx  = N / 64;
    const int ndq  = nbx * (K / 256);

    prologue_kernel<<<ncvt + ndq, 256, 0, stream>>>(
        x, xb, nx, ncvt, qw, scales, zps, deqT, N, K, nbx);
    gemm_bf16_bt<<<dim3(N / BN, M / BM), 256, 0, stream>>>(xb, deqT, bias, out, M, N, K);
}

// Round 6
// 164.450 us; speedup vs baseline: 1.3133x; 1.0567x over previous
//
#include <hip/hip_runtime.h>
#include <cstdint>
#include <cstddef>

typedef __attribute__((ext_vector_type(8))) short short8;
typedef __attribute__((ext_vector_type(4))) float floatx4;

typedef __attribute__((address_space(1))) const void gvoid_t;
typedef __attribute__((address_space(3))) void lvoid_t;

// fp32 -> bf16 with round-to-nearest-even (bit pattern as short)
__device__ inline short f2bf(float f) {
    unsigned u = __float_as_uint(f);
    u = (u + 0x7FFFu + ((u >> 16) & 1u)) >> 16;
    return (short)u;
}

// ---------------------------------------------------------------------------
// Merged prologue: blocks [0,ncvt) convert x fp32->bf16; blocks [ncvt,..)
// dequantize qweight into transposed bf16 deqT [N][K]. Both memory-bound;
// 93MB total ~= 15us at 6.3TB/s (measured at roofline).
// ---------------------------------------------------------------------------
__global__ __launch_bounds__(256) void prologue_kernel(
    const float* __restrict__ x, short* __restrict__ xb, long long nx, int ncvt,
    const int* __restrict__ qw, const float* __restrict__ scales,
    const float* __restrict__ zps, short* __restrict__ deqT,
    int N, int K, int nbx)
{
    __shared__ int lds_q[32 * 65];
    const int t = threadIdx.x;

    if ((int)blockIdx.x < ncvt) {
        // ---- convert x ----
        long long i = ((long long)blockIdx.x * 256 + t) * 8;
        if (i + 8 > nx) return;
        const float4* p = (const float4*)(x + i);
        float4 v0 = p[0];
        float4 v1 = p[1];
        short8 h;
        h[0] = f2bf(v0.x); h[1] = f2bf(v0.y); h[2] = f2bf(v0.z); h[3] = f2bf(v0.w);
        h[4] = f2bf(v1.x); h[5] = f2bf(v1.y); h[6] = f2bf(v1.z); h[7] = f2bf(v1.w);
        *(short8*)(xb + i) = h;
        return;
    }

    // ---- dequant ----
    const int b2 = (int)blockIdx.x - ncvt;
    const int n0 = (b2 % nbx) * 64;
    const int r0 = (b2 / nbx) * 32;   // qweight row tile (32 rows = 256 k)

    // Phase 1: coalesced load of the 32x64 int32 tile into LDS (pad 65)
    #pragma unroll
    for (int v = 0; v < 2; ++v) {
        int idx = t + v * 256;            // 0..511 int4-chunks
        int row = idx >> 4;               // 16 int4 per 64-col row
        int c4  = (idx & 15) * 4;
        const int4 q4 = *(const int4*)(qw + (size_t)(r0 + row) * N + n0 + c4);
        int base = row * 65 + c4;
        lds_q[base + 0] = q4.x;
        lds_q[base + 1] = q4.y;
        lds_q[base + 2] = q4.z;
        lds_q[base + 3] = q4.w;
    }
    __syncthreads();

    const int L  = t & 63;
    const int w  = t >> 6;
    const int rq = L & 31;            // qw row this lane unpacks
    const int hi = L >> 5;            // 0: row 2p, 1: row 2p+1
    const int g  = (r0 + rq) >> 4;    // quant group of this lane's 8 k-values

    #pragma unroll
    for (int it = 0; it < 8; ++it) {
        const int p  = w * 8 + it;    // row-pair index 0..31
        const int nl = 2 * p + hi;    // local n row 0..63

        float s = scales[(size_t)g * N + n0 + nl];
        s = fminf(fmaxf(s, 1e-5f), 1e4f);
        float z = rintf(zps[(size_t)g * N + n0 + nl]);
        z = fminf(fmaxf(z, 0.0f), 15.0f);

        const int q = lds_q[rq * 65 + nl];
        short8 h;
        #pragma unroll
        for (int j = 0; j < 8; ++j) {
            float f = (float)((q >> (4 * j)) & 15);
            h[j] = f2bf((f - z) * s);
        }
        // lanes 0-31: 512B contiguous (row 2p), lanes 32-63: row 2p+1
        *(short8*)(deqT + (size_t)(n0 + nl) * K + (size_t)(r0 + rq) * 8) = h;
    }
}

// ---------------------------------------------------------------------------
// Kernel 2: bf16 GEMM, C = A[M][K] * Bt[N][K]^T + bias, fp32 out.
//
// FINAL = R0/R5 structure (best measured across the session: 78us GEMM,
// 888 TF, 0 bank conflicts, 2 blocks/CU): single-barrier double-buffered
// BK=64 K-loop, 128x128 tile, 4 waves, 16x16x32 MFMA, XCD-aware swizzle.
//
// Session evidence for why THIS config (R1-R4 all regressed):
//  - R1 (4-phase, fence-before-barrier): 111us. Pre-barrier lgkmcnt(0)
//    serializes LDS drain / barrier / MFMA (m233 pathology).
//  - R2 (2-phase triple-buffer, counted vmcnt): 90us = the documented
//    "2-phase band" (m230/m233/m248), below this m97-band baseline.
//  - R3 (256^2 8-phase split-K port): 127us. 1 block/CU (acc[8][4] ~250
//    regs/wave -> 8 waves/CU max) with no cross-block overlap; intra-block
//    pipeline failed to engage (m232 failure mode) + atomic epilogue tax.
//  - R4 (32x32x16 MFMA): 95.5us. Structurally 4-way LDS bank conflict
//    (8.4M cycles ~= +16us): 32 same-chunk lanes can only spread over 8
//    16B positions at 128B row stride; row-pad fix is incompatible with
//    global_load_lds linear dest (m104/m173). Also FETCH unchanged ->
//    C-RFO theory disproven.
// Within the m97 family the tile sweep is already measured: 128^2 = 912 >
// 128x256 = 823 > 256^2 = 792 TF (m103/m105/m112); BK=128 regresses
// (m132); T5/T8/T19/explicit-pipelining all null on this base
// (m190/m254/m137/m131-m141). Remaining gap to peak = the documented
// m97-structure barrier-drain ceiling (~900 TF).
// ---------------------------------------------------------------------------
#define BM 128
#define BN 128
#define BK 64

__global__ __launch_bounds__(256) void gemm_bf16_bt(
    const short* __restrict__ A, const short* __restrict__ Bt,
    const float* __restrict__ bias, float* __restrict__ C,
    int M, int N, int K)
{
    __shared__ __align__(16) short a_lds[2][BM * BK];   // 2 x 16 KB
    __shared__ __align__(16) short b_lds[2][BN * BK];   // 2 x 16 KB

    const int t  = threadIdx.x;
    const int L  = t & 63;
    const int w  = t >> 6;

    // XCD swizzle: id%8 = XCD (dispatch round-robins consecutive ids across
    // XCDs). XCD k gets n-tiles 4k..4k+3 for every m-tile.
    const int nbn = N / BN;                    // n-tiles (32)
    const int id  = blockIdx.y * gridDim.x + blockIdx.x;
    const int xcd = id & 7;
    const int loc = id >> 3;                   // 0..63 per XCD
    const int gsz = nbn / 8;                   // n-tiles per XCD group (4)
    const int nt  = xcd * gsz + (loc % gsz);
    const int mt  = loc / gsz;
    const int m0  = mt * BM;
    const int n0  = nt * BN;

    const int wm = (w & 1) * 64;
    const int wn = (w >> 1) * 64;

    floatx4 acc[4][4] = {};

    // staging: per inst i, wave w covers rows w*8 + 32*i + (L>>3);
    // LDS slot = uniform base + lane*16B (hardware-enforced order).
    const int sr = L >> 3;            // row within the wave's 8-row window
    const int sc = L & 7;             // 16B-chunk position within row (0..7)
    const int gc = sc ^ sr;           // global chunk staged at LDS pos sc
    const short* ag = A  + (size_t)(m0 + w * 8 + sr) * K + gc * 8;
    const short* bg = Bt + (size_t)(n0 + w * 8 + sr) * K + gc * 8;
    const int dst = (w * 8) * BK;     // wave-uniform offset within buffer

    const int NK = K / BK;

    // prologue: stage tile 0 into buffer 0
    #pragma unroll
    for (int i = 0; i < 4; ++i) {
        __builtin_amdgcn_global_load_lds(
            (gvoid_t*)(ag + (size_t)i * 32 * K),
            (lvoid_t*)(&a_lds[0][dst + i * 32 * BK]), 16, 0, 0);
        __builtin_amdgcn_global_load_lds(
            (gvoid_t*)(bg + (size_t)i * 32 * K),
            (lvoid_t*)(&b_lds[0][dst + i * 32 * BK]), 16, 0, 0);
    }

    for (int ti = 0; ti < NK; ++ti) {
        const int cur = ti & 1;
        // drains cur's loads (in flight for a full compute phase, except ti=0)
        // + guarantees all waves finished reading buf cur^1
        __syncthreads();

        if (ti + 1 < NK) {
            const int kn = (ti + 1) * BK;
            #pragma unroll
            for (int i = 0; i < 4; ++i) {
                __builtin_amdgcn_global_load_lds(
                    (gvoid_t*)(ag + (size_t)i * 32 * K + kn),
                    (lvoid_t*)(&a_lds[cur ^ 1][dst + i * 32 * BK]), 16, 0, 0);
                __builtin_amdgcn_global_load_lds(
                    (gvoid_t*)(bg + (size_t)i * 32 * K + kn),
                    (lvoid_t*)(&b_lds[cur ^ 1][dst + i * 32 * BK]), 16, 0, 0);
            }
        }

        #pragma unroll
        for (int s = 0; s < 2; ++s) {
            // global chunk c = s*4 + (L>>4) of row r (r&7 == L&7):
            const int p = (s * 4 + (L >> 4)) ^ (L & 7);  // swizzled LDS pos
            short8 af[4], bfr[4];
            #pragma unroll
            for (int i = 0; i < 4; ++i)
                af[i] = *(const short8*)(&a_lds[cur][(wm + 16 * i + (L & 15)) * BK + p * 8]);
            #pragma unroll
            for (int j = 0; j < 4; ++j)
                bfr[j] = *(const short8*)(&b_lds[cur][(wn + 16 * j + (L & 15)) * BK + p * 8]);
            #pragma unroll
            for (int i = 0; i < 4; ++i) {
                #pragma unroll
                for (int j = 0; j < 4; ++j)
                    acc[i][j] = __builtin_amdgcn_mfma_f32_16x16x32_bf16(
                        af[i], bfr[j], acc[i][j], 0, 0, 0);
            }
        }
    }

    // Epilogue: C/D layout col = lane&15, row = (lane>>4)*4 + reg  (m89/m91)
    float bv[4];
    #pragma unroll
    for (int j = 0; j < 4; ++j)
        bv[j] = bias[n0 + wn + 16 * j + (L & 15)];
    const int col0 = n0 + wn + (L & 15);
    #pragma unroll
    for (int i = 0; i < 4; ++i) {
        const int row0 = m0 + wm + 16 * i + (L >> 4) * 4;
        #pragma unroll
        for (int r = 0; r < 4; ++r) {
            float* outr = C + (size_t)(row0 + r) * N + col0;
            #pragma unroll
            for (int j = 0; j < 4; ++j)
                outr[16 * j] = acc[i][j][r] + bv[j];
        }
    }
}

// ---------------------------------------------------------------------------
extern "C" void kernel_launch(void* const* d_in, const int* in_sizes, int n_in,
                              void* d_out, int out_size, void* d_ws, size_t ws_size,
                              hipStream_t stream)
{
    const float* x      = (const float*)d_in[0];
    const float* scales = (const float*)d_in[1];
    const float* zps    = (const float*)d_in[2];
    const float* bias   = (const float*)d_in[3];
    const int*   qw     = (const int*)d_in[4];

    const int N = in_sizes[3];          // outfeatures (bias length)
    const int G = in_sizes[1] / N;      // num groups
    const int K = G * 128;              // infeatures
    const int M = in_sizes[0] / K;      // tokens

    short* xb   = (short*)d_ws;                       // M*K bf16
    short* deqT = xb + (size_t)M * K;                 // N*K bf16
    float* out  = (float*)d_out;

    const long long nx = (long long)M * K;
    const int ncvt = (int)(nx / 2048);
    const int nbx  = N / 64;
    const int ndq  = nbx * (K / 256);

    prologue_kernel<<<ncvt + ndq, 256, 0, stream>>>(
        x, xb, nx, ncvt, qw, scales, zps, deqT, N, K, nbx);
    gemm_bf16_bt<<<dim3(N / BN, M / BM), 256, 0, stream>>>(xb, deqT, bias, out, M, N, K);
}